// Round 5
// baseline (600.265 us; speedup 1.0000x reference)
//
#include <hip/hip_runtime.h>
#include <math.h>

#define T_LEN 4096
#define B_SZ  512

// emission: fl(fl(fl(-0.5*x)*x) - fl32(0.5*log(2*pi)))
__device__ __forceinline__ float emis(float xv) {
    float a = __fmul_rn(-0.5f, xv);
    float b = __fmul_rn(a, xv);
    return __fsub_rn(b, (float)0.9189385332046727);
}

// ---------------------------------------------------------------------------
// Fused prep+emit. Block 0 (tid<256) additionally computes
// logA[i*16+j] = fl32(log64(trans[i][j])) - fl32(log64(rowsum_i)) (numpy
// pairwise-16 rowsum) and the transpose logAT for k_psi scalar loads.
__global__ __launch_bounds__(256) void k_emit(const float* __restrict__ x,
                                              float* __restrict__ E,
                                              const float* __restrict__ hmm,
                                              float* __restrict__ logA,
                                              float* __restrict__ logAT) {
    int tid = threadIdx.x;
    if (blockIdx.x == 0) {
        int i = tid >> 4, j = tid & 15;
        const float* row = hmm + i * 16;
        float r[8];
#pragma unroll
        for (int k = 0; k < 8; ++k) r[k] = __fadd_rn(row[k], row[k + 8]);
        float s = __fadd_rn(
            __fadd_rn(__fadd_rn(r[0], r[1]), __fadd_rn(r[2], r[3])),
            __fadd_rn(__fadd_rn(r[4], r[5]), __fadd_rn(r[6], r[7])));
        float la = (float)log((double)row[j]);
        float ls = (float)log((double)s);
        float v = __fsub_rn(la, ls);
        logA[tid] = v;
        logAT[j * 16 + i] = v;
    }
    int i = blockIdx.x * 256 + tid;
    float4 v = ((const float4*)x)[i];
    float4 e;
    e.x = emis(v.x); e.y = emis(v.y); e.z = emis(v.z); e.w = emis(v.w);
    ((float4*)E)[i] = e;
}

// ---------------------------------------------------------------------------
// Forward: 8 batches/wave. Lane-group g (16 lanes) runs TWO batches (chains
// A,B) with manually interleaved instruction streams — chain B's slots fill
// chain A's dependency stalls (single wave per CU, latency-bound regime).
// Rotation fused into the score add via inline-asm v_add_f32_dpp; a[] is
// lane-only (shared by both chains), self-calibrated via builtin row_ror.
#define DPP_ROR0(K, SRC) __builtin_amdgcn_update_dpp(0, (SRC), 0x120 + (K), 0xF, 0xF, false)
#define M3(x, y, z) fmaxf(fmaxf(x, y), z)

#define ADDPP(DST, SRCD, K)                                                           \
    asm("v_add_f32_dpp %0, %1, %2 row_ror:" #K " row_mask:0xf bank_mask:0xf"          \
        : "=v"(DST) : "v"(SRCD), "v"(a[K]))

#define STEP2(ETA, ETB, ROWIDX)                                                       \
    {                                                                                 \
        float sA0 = __fadd_rn(dA, a[0]);     float sB0 = __fadd_rn(dB, a[0]);         \
        float sA1, sA2, sA3, sA4, sA5, sA6, sA7, sA8, sA9, sA10, sA11, sA12,          \
              sA13, sA14, sA15;                                                       \
        float sB1, sB2, sB3, sB4, sB5, sB6, sB7, sB8, sB9, sB10, sB11, sB12,          \
              sB13, sB14, sB15;                                                       \
        ADDPP(sA1, dA, 1);   ADDPP(sB1, dB, 1);                                       \
        ADDPP(sA2, dA, 2);   ADDPP(sB2, dB, 2);                                       \
        ADDPP(sA3, dA, 3);   ADDPP(sB3, dB, 3);                                       \
        ADDPP(sA4, dA, 4);   ADDPP(sB4, dB, 4);                                       \
        ADDPP(sA5, dA, 5);   ADDPP(sB5, dB, 5);                                       \
        ADDPP(sA6, dA, 6);   ADDPP(sB6, dB, 6);                                       \
        ADDPP(sA7, dA, 7);   ADDPP(sB7, dB, 7);                                       \
        ADDPP(sA8, dA, 8);   ADDPP(sB8, dB, 8);                                       \
        ADDPP(sA9, dA, 9);   ADDPP(sB9, dB, 9);                                       \
        ADDPP(sA10, dA, 10); ADDPP(sB10, dB, 10);                                     \
        ADDPP(sA11, dA, 11); ADDPP(sB11, dB, 11);                                     \
        ADDPP(sA12, dA, 12); ADDPP(sB12, dB, 12);                                     \
        ADDPP(sA13, dA, 13); ADDPP(sB13, dB, 13);                                     \
        ADDPP(sA14, dA, 14); ADDPP(sB14, dB, 14);                                     \
        ADDPP(sA15, dA, 15); ADDPP(sB15, dB, 15);                                     \
        float uA0 = M3(sA0, sA1, sA2);       float uB0 = M3(sB0, sB1, sB2);           \
        float uA1 = M3(sA3, sA4, sA5);       float uB1 = M3(sB3, sB4, sB5);           \
        float uA2 = M3(sA6, sA7, sA8);       float uB2 = M3(sB6, sB7, sB8);           \
        float uA3 = M3(sA9, sA10, sA11);     float uB3 = M3(sB9, sB10, sB11);         \
        float uA4 = M3(sA12, sA13, sA14);    float uB4 = M3(sB12, sB13, sB14);        \
        float mA = fmaxf(M3(uA0, uA1, uA2), M3(uA3, uA4, sA15));                      \
        float mB = fmaxf(M3(uB0, uB1, uB2), M3(uB3, uB4, sB15));                      \
        dA = __fadd_rn(mA, ETA);             dB = __fadd_rn(mB, ETB);                 \
        dcolA[(ROWIDX) * 16] = dA;           dcolB[(ROWIDX) * 16] = dB;               \
    }

__global__ __launch_bounds__(64) void k_fwd(const float* __restrict__ E,
                                            const float* __restrict__ logA,
                                            float* __restrict__ dchunk,
                                            float* __restrict__ carry) {
    const int lane = threadIdx.x;
    const int j = lane & 15;
    const int bA = blockIdx.x * 8 + (lane >> 4);
    const int bB = bA + 4;
    float a[16];
    a[0] = logA[j * 16 + j];
#define LOADA(K) { int sk = DPP_ROR0(K, j); a[K] = logA[sk * 16 + j]; }
    LOADA(1)  LOADA(2)  LOADA(3)  LOADA(4)  LOADA(5)
    LOADA(6)  LOADA(7)  LOADA(8)  LOADA(9)  LOADA(10)
    LOADA(11) LOADA(12) LOADA(13) LOADA(14) LOADA(15)
#undef LOADA
    const float* ebA = E + bA * T_LEN;
    const float* ebB = E + bB * T_LEN;
    float* dcolA = dchunk + bA * T_LEN * 16 + j;
    float* dcolB = dchunk + bB * T_LEN * 16 + j;

    // t = 0: delta0 = fl(log_pi[j] + E[b][0]); log_pi == logA row 0.
    float lp = logA[j];
    float dA = __fadd_rn(lp, ebA[0]);
    float dB = __fadd_rn(lp, ebB[0]);
    dcolA[0] = dA;
    dcolB[0] = dB;

    // steps 1..3 to 4-align t for float4 E loads
    int t = 1;
    for (; t < 4; ++t) { STEP2(ebA[t], ebB[t], t) }

    float4 qA0 = *(const float4*)(ebA + t);
    float4 qA1 = *(const float4*)(ebA + t + 4);
    float4 qA2 = *(const float4*)(ebA + t + 8);
    float4 qA3 = *(const float4*)(ebA + t + 12);
    float4 qB0 = *(const float4*)(ebB + t);
    float4 qB1 = *(const float4*)(ebB + t + 4);
    float4 qB2 = *(const float4*)(ebB + t + 8);
    float4 qB3 = *(const float4*)(ebB + t + 12);
    while (t + 15 <= T_LEN - 1) {
        STEP2(qA0.x, qB0.x, t)      STEP2(qA0.y, qB0.y, t + 1)
        STEP2(qA0.z, qB0.z, t + 2)  STEP2(qA0.w, qB0.w, t + 3)
        qA0 = *(const float4*)(ebA + t + 16);
        qB0 = *(const float4*)(ebB + t + 16);
        STEP2(qA1.x, qB1.x, t + 4)  STEP2(qA1.y, qB1.y, t + 5)
        STEP2(qA1.z, qB1.z, t + 6)  STEP2(qA1.w, qB1.w, t + 7)
        qA1 = *(const float4*)(ebA + t + 20);
        qB1 = *(const float4*)(ebB + t + 20);
        STEP2(qA2.x, qB2.x, t + 8)  STEP2(qA2.y, qB2.y, t + 9)
        STEP2(qA2.z, qB2.z, t + 10) STEP2(qA2.w, qB2.w, t + 11)
        qA2 = *(const float4*)(ebA + t + 24);
        qB2 = *(const float4*)(ebB + t + 24);
        STEP2(qA3.x, qB3.x, t + 12) STEP2(qA3.y, qB3.y, t + 13)
        STEP2(qA3.z, qB3.z, t + 14) STEP2(qA3.w, qB3.w, t + 15)
        qA3 = *(const float4*)(ebA + t + 28);
        qB3 = *(const float4*)(ebB + t + 28);
        t += 16;
    }
    for (; t <= T_LEN - 1; ++t) { STEP2(ebA[t], ebB[t], t) }
    carry[bA * 16 + j] = dA;
    carry[bB * 16 + j] = dB;
}

// ---------------------------------------------------------------------------
// psi: one thread per (b,t). AT columns via SCALAR path (wave-uniform logAT,
// jj loop not unrolled) -> zero LDS traffic.
__global__ __launch_bounds__(256) void k_psi(const float* __restrict__ dchunk,
                                             const float* __restrict__ logAT,
                                             unsigned char* __restrict__ psi) {
    int tt = blockIdx.x * 256 + threadIdx.x;
    if (tt >= T_LEN - 1) return;
    int b = blockIdx.y;
    const float4* dr = (const float4*)(dchunk + ((size_t)b * T_LEN + tt) * 16);
    float4 v0 = dr[0], v1 = dr[1], v2 = dr[2], v3 = dr[3];
    float dd[16] = {v0.x, v0.y, v0.z, v0.w, v1.x, v1.y, v1.z, v1.w,
                    v2.x, v2.y, v2.z, v2.w, v3.x, v3.y, v3.z, v3.w};
    unsigned long long pk = 0ull;
#pragma clang loop unroll(disable)
    for (int jj = 0; jj < 16; ++jj) {
        const float* col = logAT + (jj << 4);
        float best = __fadd_rn(dd[0], col[0]);
        int arg = 0;
#pragma unroll
        for (int i = 1; i < 16; ++i) {
            float s = __fadd_rn(dd[i], col[i]);
            if (s > best) arg = i;  // first-wins tie rule (i ascending)
            best = fmaxf(best, s);
        }
        pk |= (unsigned long long)arg << (jj * 4);
    }
    unsigned w[4];
#pragma unroll
    for (int q = 0; q < 4; ++q) {
        unsigned h = (unsigned)(pk >> (16 * q)) & 0xFFFFu;
        w[q] = (h & 0xFu) | ((h & 0xF0u) << 4) | ((h & 0xF00u) << 8) | ((h & 0xF000u) << 12);
    }
    int t = 1 + tt;
    *((uint4*)(psi + ((size_t)b * T_LEN + t) * 16)) = make_uint4(w[0], w[1], w[2], w[3]);
}

// ---------------------------------------------------------------------------
__global__ __launch_bounds__(256) void k_maps(const unsigned char* __restrict__ psi,
                                              unsigned char* __restrict__ M) {
    __shared__ unsigned char buf[16][1024];
    int tid = threadIdx.x;
    int grp = tid >> 4, lane = tid & 15;
    int g = blockIdx.x * 16 + grp;  // g = b*64 + c
    int b = g >> 6, c = g & 63;
    int t_lo = c * 64;
    int t_hi = t_lo + 64; if (t_hi > T_LEN - 1) t_hi = T_LEN - 1;
    int n16 = t_hi - t_lo;
    const uint4* src = (const uint4*)(psi + ((size_t)b * T_LEN + t_lo + 1) * 16);
    uint4* dst = (uint4*)buf[grp];
    for (int r = lane; r < n16; r += 16) dst[r] = src[r];
    __syncthreads();
    int v = lane;
    for (int t = t_hi; t > t_lo; --t) v = buf[grp][(t - t_lo - 1) * 16 + v];
    M[(size_t)g * 16 + lane] = (unsigned char)v;
}

__global__ __launch_bounds__(256) void k_bound(const float* __restrict__ carry,
                                               const unsigned char* __restrict__ M,
                                               unsigned char* __restrict__ Eb,
                                               int* __restrict__ out) {
    int b = blockIdx.x * 256 + threadIdx.x;
    if (b >= B_SZ) return;
    const float* dT = carry + b * 16;
    float best = dT[0]; int zT = 0;
#pragma unroll
    for (int i = 1; i < 16; ++i) {
        float s = dT[i];
        if (s > best) zT = i;
        best = fmaxf(best, s);
    }
    out[(size_t)b * T_LEN + (T_LEN - 1)] = zT;
    int z = zT;
    for (int c = 63; c >= 0; --c) {
        Eb[b * 64 + c] = (unsigned char)z;
        z = M[((size_t)b * 64 + c) * 16 + z];
    }
}

__global__ __launch_bounds__(256) void k_walk(const unsigned char* __restrict__ psi,
                                              const unsigned char* __restrict__ Eb,
                                              int* __restrict__ out) {
    __shared__ unsigned char buf[16][1024];
    int tid = threadIdx.x;
    int grp = tid >> 4, lane = tid & 15;
    int g = blockIdx.x * 16 + grp;  // g = b*64 + c
    int b = g >> 6, c = g & 63;
    int t_lo = c * 64;
    int t_hi = t_lo + 64; if (t_hi > T_LEN - 1) t_hi = T_LEN - 1;
    int n16 = t_hi - t_lo;
    const uint4* src = (const uint4*)(psi + ((size_t)b * T_LEN + t_lo + 1) * 16);
    uint4* dst = (uint4*)buf[grp];
    for (int r = lane; r < n16; r += 16) dst[r] = src[r];
    __syncthreads();
    if (lane == 0) {
        int cur = Eb[b * 64 + c];
        int* ob = out + (size_t)b * T_LEN;
        for (int t = t_hi; t > t_lo; --t) {
            cur = buf[grp][(t - t_lo - 1) * 16 + cur];
            ob[t - 1] = cur;
        }
    }
}

// ---------------------------------------------------------------------------
extern "C" void kernel_launch(void* const* d_in, const int* in_sizes, int n_in,
                              void* d_out, int out_size, void* d_ws, size_t ws_size,
                              hipStream_t stream) {
    (void)in_sizes; (void)n_in; (void)out_size; (void)ws_size;
    const float* x   = (const float*)d_in[0];   // [512][4096] fp32
    const float* hmm = (const float*)d_in[1];   // [64][16][16] fp32 (only [0] used)
    int* out = (int*)d_out;                     // [512][4096] int32

    char* w = (char*)d_ws;
    float* logA  = (float*)w;                                  // 1KB
    float* logAT = (float*)(w + 1024);                         // 1KB (4KB slot)
    float* carry = (float*)(w + 4096);                         // 32KB
    unsigned char* psi = (unsigned char*)(w + 4096 + 32768);   // 33.55MB
    unsigned char* M   = psi + (size_t)B_SZ * T_LEN * 16;      // 512KB
    unsigned char* Eb  = M + (size_t)B_SZ * 64 * 16;           // 32KB
    float* dchunk = (float*)(Eb + (size_t)B_SZ * 64);          // 134.2MB
    float* Em = (float*)psi;  // emissions alias psi region (consumed pre-k_psi)

    hipLaunchKernelGGL(k_emit, dim3((B_SZ * T_LEN / 4) / 256), dim3(256), 0, stream,
                       x, Em, hmm, logA, logAT);

    hipLaunchKernelGGL(k_fwd, dim3(B_SZ / 8), dim3(64), 0, stream,
                       Em, logA, dchunk, carry);

    hipLaunchKernelGGL(k_psi, dim3((T_LEN - 1 + 255) / 256, B_SZ), dim3(256), 0, stream,
                       dchunk, logAT, psi);

    hipLaunchKernelGGL(k_maps,  dim3(2048), dim3(256), 0, stream, psi, M);
    hipLaunchKernelGGL(k_bound, dim3(2),    dim3(256), 0, stream, carry, M, Eb, out);
    hipLaunchKernelGGL(k_walk,  dim3(2048), dim3(256), 0, stream, psi, Eb, out);
}

// Round 6
// 542.474 us; speedup vs baseline: 1.1065x; 1.1065x over previous
//
#include <hip/hip_runtime.h>
#include <math.h>

#define T_LEN 4096
#define B_SZ  512

// emission: fl(fl(fl(-0.5*x)*x) - fl32(0.5*log(2*pi)))
__device__ __forceinline__ float emis(float xv) {
    float a = __fmul_rn(-0.5f, xv);
    float b = __fmul_rn(a, xv);
    return __fsub_rn(b, (float)0.9189385332046727);
}

// ---------------------------------------------------------------------------
// Fused prep+emit. Block 0 computes logA (numpy pairwise-16 rowsum, fp64 log
// rounded to fp32) and logAT; all blocks compute E = emis(x).
__global__ __launch_bounds__(256) void k_emit(const float* __restrict__ x,
                                              float* __restrict__ E,
                                              const float* __restrict__ hmm,
                                              float* __restrict__ logA,
                                              float* __restrict__ logAT) {
    int tid = threadIdx.x;
    if (blockIdx.x == 0) {
        int i = tid >> 4, j = tid & 15;
        const float* row = hmm + i * 16;
        float r[8];
#pragma unroll
        for (int k = 0; k < 8; ++k) r[k] = __fadd_rn(row[k], row[k + 8]);
        float s = __fadd_rn(
            __fadd_rn(__fadd_rn(r[0], r[1]), __fadd_rn(r[2], r[3])),
            __fadd_rn(__fadd_rn(r[4], r[5]), __fadd_rn(r[6], r[7])));
        float la = (float)log((double)row[j]);
        float ls = (float)log((double)s);
        float v = __fsub_rn(la, ls);
        logA[tid] = v;
        logAT[j * 16 + i] = v;
    }
    int i = blockIdx.x * 256 + tid;
    float4 v = ((const float4*)x)[i];
    float4 e;
    e.x = emis(v.x); e.y = emis(v.y); e.z = emis(v.z); e.w = emis(v.w);
    ((float4*)E)[i] = e;
}

// ---------------------------------------------------------------------------
// Forward, hybrid exchange: 4 batches/wave (16 lanes each). Sources covered
// by self-add + 10 v_add_f32_dpp (row_ror 1..10) + 5 via an LDS window:
// each lane dup-publishes d (addr j and j+16), then reads 5 consecutive
// floats starting at a self-calibrated base = the 5 states ror11..ror15.
// LDS round-trip latency hides under the ~70-cyc DPP block. All adds
// __fadd_rn; max-tree reassociation is rounding-free => bit-exact.
#define DPP_ROR0(K, SRC) __builtin_amdgcn_update_dpp(0, (SRC), 0x120 + (K), 0xF, 0xF, false)
#define M3(x, y, z) fmaxf(fmaxf(x, y), z)

#define ADDPP(DST, K)                                                                 \
    asm("v_add_f32_dpp %0, %1, %2 row_ror:" #K " row_mask:0xf bank_mask:0xf"          \
        : "=v"(DST) : "v"(d), "v"(a[K]))

#define STEP(ET, ROWIDX)                                                              \
    {                                                                                 \
        shg[j] = d;                                                                   \
        shg[16 + j] = d;                                                              \
        float w0 = shg[base];     float w1 = shg[base + 1];                           \
        float w2 = shg[base + 2]; float w3 = shg[base + 3];                           \
        float w4 = shg[base + 4];                                                     \
        float s0 = __fadd_rn(d, a[0]);                                                \
        float s1, s2, s3, s4, s5, s6, s7, s8, s9, s10;                                \
        ADDPP(s1, 1); ADDPP(s2, 2); ADDPP(s3, 3); ADDPP(s4, 4); ADDPP(s5, 5);         \
        ADDPP(s6, 6); ADDPP(s7, 7); ADDPP(s8, 8); ADDPP(s9, 9); ADDPP(s10, 10);       \
        float u0 = M3(s0, s1, s2), u1 = M3(s3, s4, s5), u2 = M3(s6, s7, s8);          \
        float tD = fmaxf(M3(u0, u1, u2), fmaxf(s9, s10));                             \
        float l0 = __fadd_rn(w0, aL0); float l1 = __fadd_rn(w1, aL1);                 \
        float l2 = __fadd_rn(w2, aL2); float l3 = __fadd_rn(w3, aL3);                 \
        float l4 = __fadd_rn(w4, aL4);                                                \
        float m = M3(fmaxf(tD, fmaxf(l3, l4)), M3(l0, l1, l2), tD);                   \
        d = __fadd_rn(m, ET);                                                         \
        dcol[(ROWIDX) * 16] = d;                                                      \
    }

__global__ __launch_bounds__(64) void k_fwd(const float* __restrict__ E,
                                            const float* __restrict__ logA,
                                            float* __restrict__ dchunk,
                                            float* __restrict__ carry) {
    __shared__ float sh[4 * 40];  // per-group 32 floats (dup), stride 40 = bank spread
    const int lane = threadIdx.x;
    const int j = lane & 15;
    const int g = lane >> 4;
    const int b = blockIdx.x * 4 + g;
    float* shg = sh + g * 40;

    // DPP-side coefficients (self-calibrated: a[k] pairs with ror_k's source)
    float a[11];
    a[0] = logA[j * 16 + j];
#define LOADA(K) { int sk = DPP_ROR0(K, j); a[K] = logA[sk * 16 + j]; }
    LOADA(1) LOADA(2) LOADA(3) LOADA(4) LOADA(5)
    LOADA(6) LOADA(7) LOADA(8) LOADA(9) LOADA(10)
#undef LOADA
    // LDS-window: the 5 states {ror11..ror15} are consecutive mod 16;
    // find ascending base regardless of rotation direction.
    int w11 = DPP_ROR0(11, j);
    int w15 = DPP_ROR0(15, j);
    int base = (((w11 + 4) & 15) == w15) ? w11 : w15;
    float aL0 = logA[((base + 0) & 15) * 16 + j];
    float aL1 = logA[((base + 1) & 15) * 16 + j];
    float aL2 = logA[((base + 2) & 15) * 16 + j];
    float aL3 = logA[((base + 3) & 15) * 16 + j];
    float aL4 = logA[((base + 4) & 15) * 16 + j];

    const float* eb = E + b * T_LEN;
    float* dcol = dchunk + b * T_LEN * 16 + j;

    // t = 0: delta0 = fl(log_pi[j] + E[b][0]); log_pi == logA row 0.
    float d = __fadd_rn(logA[j], eb[0]);
    dcol[0] = d;

    int t = 1;
    for (; t < 4; ++t) { STEP(eb[t], t) }

    float4 q0 = *(const float4*)(eb + t);
    float4 q1 = *(const float4*)(eb + t + 4);
    float4 q2 = *(const float4*)(eb + t + 8);
    float4 q3 = *(const float4*)(eb + t + 12);
    while (t + 15 <= T_LEN - 1) {
        STEP(q0.x, t) STEP(q0.y, t + 1) STEP(q0.z, t + 2) STEP(q0.w, t + 3)
        q0 = *(const float4*)(eb + t + 16);
        STEP(q1.x, t + 4) STEP(q1.y, t + 5) STEP(q1.z, t + 6) STEP(q1.w, t + 7)
        q1 = *(const float4*)(eb + t + 20);
        STEP(q2.x, t + 8) STEP(q2.y, t + 9) STEP(q2.z, t + 10) STEP(q2.w, t + 11)
        q2 = *(const float4*)(eb + t + 24);
        STEP(q3.x, t + 12) STEP(q3.y, t + 13) STEP(q3.z, t + 14) STEP(q3.w, t + 15)
        q3 = *(const float4*)(eb + t + 28);
        t += 16;
    }
    for (; t <= T_LEN - 1; ++t) { STEP(eb[t], t) }
    carry[b * 16 + j] = d;
}

// ---------------------------------------------------------------------------
// psi: one thread per (b,t). AT columns via SCALAR path (wave-uniform logAT).
__global__ __launch_bounds__(256) void k_psi(const float* __restrict__ dchunk,
                                             const float* __restrict__ logAT,
                                             unsigned char* __restrict__ psi) {
    int tt = blockIdx.x * 256 + threadIdx.x;
    if (tt >= T_LEN - 1) return;
    int b = blockIdx.y;
    const float4* dr = (const float4*)(dchunk + ((size_t)b * T_LEN + tt) * 16);
    float4 v0 = dr[0], v1 = dr[1], v2 = dr[2], v3 = dr[3];
    float dd[16] = {v0.x, v0.y, v0.z, v0.w, v1.x, v1.y, v1.z, v1.w,
                    v2.x, v2.y, v2.z, v2.w, v3.x, v3.y, v3.z, v3.w};
    unsigned long long pk = 0ull;
#pragma clang loop unroll(disable)
    for (int jj = 0; jj < 16; ++jj) {
        const float* col = logAT + (jj << 4);
        float best = __fadd_rn(dd[0], col[0]);
        int arg = 0;
#pragma unroll
        for (int i = 1; i < 16; ++i) {
            float s = __fadd_rn(dd[i], col[i]);
            if (s > best) arg = i;  // first-wins tie rule (i ascending)
            best = fmaxf(best, s);
        }
        pk |= (unsigned long long)arg << (jj * 4);
    }
    unsigned w[4];
#pragma unroll
    for (int q = 0; q < 4; ++q) {
        unsigned h = (unsigned)(pk >> (16 * q)) & 0xFFFFu;
        w[q] = (h & 0xFu) | ((h & 0xF0u) << 4) | ((h & 0xF00u) << 8) | ((h & 0xF000u) << 12);
    }
    int t = 1 + tt;
    *((uint4*)(psi + ((size_t)b * T_LEN + t) * 16)) = make_uint4(w[0], w[1], w[2], w[3]);
}

// ---------------------------------------------------------------------------
// Fused backtrace: one block per batch. Stage psi[b][1..4095] (65520B) into
// static LDS once; (1) 1024 chunk-map walkers, (2) tid0 argmax+boundary
// chain, (3) 64 chunk walkers write the path. M/Eb bounce through global ws
// with threadfence (same-block producer/consumer).
__global__ __launch_bounds__(256) void k_back(const unsigned char* __restrict__ psi,
                                              const float* __restrict__ carry,
                                              unsigned char* __restrict__ Mg,
                                              unsigned char* __restrict__ Ebg,
                                              int* __restrict__ out) {
    __shared__ uint4 sps4[T_LEN - 1];  // 65520 B
    unsigned char* sp = (unsigned char*)sps4;
    int b = blockIdx.x, tid = threadIdx.x;
    const uint4* src = (const uint4*)(psi + ((size_t)b * T_LEN + 1) * 16);
    for (int r = tid; r < T_LEN - 1; r += 256) sps4[r] = src[r];
    __syncthreads();
    // maps: 1024 walkers on 256 threads (4 rounds)
#pragma unroll
    for (int r = 0; r < 4; ++r) {
        int wk = r * 256 + tid;
        int c = wk >> 4, z = wk & 15;
        int t_lo = c * 64;
        int t_hi = t_lo + 64; if (t_hi > T_LEN - 1) t_hi = T_LEN - 1;
        int v = z;
        for (int t = t_hi; t > t_lo; --t) v = sp[(t - 1) * 16 + v];
        Mg[((size_t)b * 64 + c) * 16 + z] = (unsigned char)v;
    }
    __threadfence();
    __syncthreads();
    if (tid == 0) {
        const float* dT = carry + b * 16;
        float best = dT[0]; int zT = 0;
#pragma unroll
        for (int i = 1; i < 16; ++i) {
            float s = dT[i];
            if (s > best) zT = i;
            best = fmaxf(best, s);
        }
        out[(size_t)b * T_LEN + (T_LEN - 1)] = zT;
        int z = zT;
        const unsigned char* Mb = Mg + (size_t)b * 64 * 16;
        for (int c = 63; c >= 0; --c) {
            Ebg[b * 64 + c] = (unsigned char)z;
            z = Mb[c * 16 + z];
        }
    }
    __threadfence();
    __syncthreads();
    if (tid < 64) {
        int c = tid;
        int t_lo = c * 64;
        int t_hi = t_lo + 64; if (t_hi > T_LEN - 1) t_hi = T_LEN - 1;
        int cur = Ebg[b * 64 + c];
        int* ob = out + (size_t)b * T_LEN;
        for (int t = t_hi; t > t_lo; --t) {
            cur = sp[(t - 1) * 16 + cur];
            ob[t - 1] = cur;
        }
    }
}

// ---------------------------------------------------------------------------
extern "C" void kernel_launch(void* const* d_in, const int* in_sizes, int n_in,
                              void* d_out, int out_size, void* d_ws, size_t ws_size,
                              hipStream_t stream) {
    (void)in_sizes; (void)n_in; (void)out_size; (void)ws_size;
    const float* x   = (const float*)d_in[0];   // [512][4096] fp32
    const float* hmm = (const float*)d_in[1];   // [64][16][16] fp32 (only [0] used)
    int* out = (int*)d_out;                     // [512][4096] int32

    char* w = (char*)d_ws;
    float* logA  = (float*)w;                                  // 1KB
    float* logAT = (float*)(w + 1024);                         // 1KB (4KB slot)
    float* carry = (float*)(w + 4096);                         // 32KB
    unsigned char* psi = (unsigned char*)(w + 4096 + 32768);   // 33.55MB
    unsigned char* M   = psi + (size_t)B_SZ * T_LEN * 16;      // 512KB
    unsigned char* Eb  = M + (size_t)B_SZ * 64 * 16;           // 32KB
    float* dchunk = (float*)(Eb + (size_t)B_SZ * 64);          // 134.2MB
    float* Em = (float*)psi;  // emissions alias psi region (consumed pre-k_psi)

    hipLaunchKernelGGL(k_emit, dim3((B_SZ * T_LEN / 4) / 256), dim3(256), 0, stream,
                       x, Em, hmm, logA, logAT);

    hipLaunchKernelGGL(k_fwd, dim3(B_SZ / 4), dim3(64), 0, stream,
                       Em, logA, dchunk, carry);

    hipLaunchKernelGGL(k_psi, dim3((T_LEN - 1 + 255) / 256, B_SZ), dim3(256), 0, stream,
                       dchunk, logAT, psi);

    hipLaunchKernelGGL(k_back, dim3(B_SZ), dim3(256), 0, stream,
                       psi, carry, M, Eb, out);
}

// Round 7
// 379.828 us; speedup vs baseline: 1.5804x; 1.4282x over previous
//
#include <hip/hip_runtime.h>
#include <math.h>

#define T_LEN 4096
#define B_SZ  512

// emission: fl(fl(fl(-0.5*x)*x) - fl32(0.5*log(2*pi)))
__device__ __forceinline__ float emis(float xv) {
    float a = __fmul_rn(-0.5f, xv);
    float b = __fmul_rn(a, xv);
    return __fsub_rn(b, (float)0.9189385332046727);
}

// ---------------------------------------------------------------------------
// Fused prep+emit. Block 0 computes logA (numpy pairwise-16 rowsum, fp64 log
// rounded to fp32) and logAT; all blocks compute E = emis(x).
__global__ __launch_bounds__(256) void k_emit(const float* __restrict__ x,
                                              float* __restrict__ E,
                                              const float* __restrict__ hmm,
                                              float* __restrict__ logA,
                                              float* __restrict__ logAT) {
    int tid = threadIdx.x;
    if (blockIdx.x == 0) {
        int i = tid >> 4, j = tid & 15;
        const float* row = hmm + i * 16;
        float r[8];
#pragma unroll
        for (int k = 0; k < 8; ++k) r[k] = __fadd_rn(row[k], row[k + 8]);
        float s = __fadd_rn(
            __fadd_rn(__fadd_rn(r[0], r[1]), __fadd_rn(r[2], r[3])),
            __fadd_rn(__fadd_rn(r[4], r[5]), __fadd_rn(r[6], r[7])));
        float la = (float)log((double)row[j]);
        float ls = (float)log((double)s);
        float v = __fsub_rn(la, ls);
        logA[tid] = v;
        logAT[j * 16 + i] = v;
    }
    int i = blockIdx.x * 256 + tid;
    float4 v = ((const float4*)x)[i];
    float4 e;
    e.x = emis(v.x); e.y = emis(v.y); e.z = emis(v.z); e.w = emis(v.w);
    ((float4*)E)[i] = e;
}

// ---------------------------------------------------------------------------
// Forward (R3 champion, 136.6 cyc/step — structural floor for 15-DPP):
// 4 batches/wave, 16 lanes/batch; rotation fused into the score add via
// inline-asm v_add_f32_dpp; a[] self-calibrated via builtin row_ror.
#define DPP_ROR0(K, SRC) __builtin_amdgcn_update_dpp(0, (SRC), 0x120 + (K), 0xF, 0xF, false)
#define M3(x, y, z) fmaxf(fmaxf(x, y), z)

#define ADDPP(DST, K)                                                                 \
    asm("v_add_f32_dpp %0, %1, %2 row_ror:" #K " row_mask:0xf bank_mask:0xf"          \
        : "=v"(DST) : "v"(d), "v"(a[K]))

#define STEPA(ET, ROWIDX)                                                             \
    {                                                                                 \
        float s0 = __fadd_rn(d, a[0]);                                                \
        float s1, s2, s3, s4, s5, s6, s7, s8, s9, s10, s11, s12, s13, s14, s15;       \
        ADDPP(s1, 1);   ADDPP(s2, 2);   ADDPP(s3, 3);   ADDPP(s4, 4);                 \
        ADDPP(s5, 5);   ADDPP(s6, 6);   ADDPP(s7, 7);   ADDPP(s8, 8);                 \
        ADDPP(s9, 9);   ADDPP(s10, 10); ADDPP(s11, 11); ADDPP(s12, 12);               \
        ADDPP(s13, 13); ADDPP(s14, 14); ADDPP(s15, 15);                               \
        float u0 = M3(s0, s1, s2),  u1 = M3(s3, s4, s5),  u2 = M3(s6, s7, s8);        \
        float u3 = M3(s9, s10, s11), u4 = M3(s12, s13, s14);                          \
        float m = fmaxf(M3(u0, u1, u2), M3(u3, u4, s15));                             \
        d = __fadd_rn(m, ET);                                                         \
        dcol[(ROWIDX) * 16] = d;                                                      \
    }

__global__ __launch_bounds__(64) void k_fwd(const float* __restrict__ E,
                                            const float* __restrict__ logA,
                                            float* __restrict__ dchunk,
                                            float* __restrict__ carry) {
    const int lane = threadIdx.x;
    const int j = lane & 15;
    const int b = blockIdx.x * 4 + (lane >> 4);
    float a[16];
    a[0] = logA[j * 16 + j];
#define LOADA(K) { int sk = DPP_ROR0(K, j); a[K] = logA[sk * 16 + j]; }
    LOADA(1)  LOADA(2)  LOADA(3)  LOADA(4)  LOADA(5)
    LOADA(6)  LOADA(7)  LOADA(8)  LOADA(9)  LOADA(10)
    LOADA(11) LOADA(12) LOADA(13) LOADA(14) LOADA(15)
#undef LOADA
    const float* eb = E + b * T_LEN;
    float* dcol = dchunk + b * T_LEN * 16 + j;

    // t = 0: delta0 = fl(log_pi[j] + E[b][0]); log_pi == logA row 0.
    float d = __fadd_rn(logA[j], eb[0]);
    dcol[0] = d;

    // steps 1..3 scalar to 4-align t for float4 E loads
    int t = 1;
    for (; t < 4; ++t) { STEPA(eb[t], t) }

    float4 q0 = *(const float4*)(eb + t);
    float4 q1 = *(const float4*)(eb + t + 4);
    float4 q2 = *(const float4*)(eb + t + 8);
    float4 q3 = *(const float4*)(eb + t + 12);
    while (t + 15 <= T_LEN - 1) {
        STEPA(q0.x, t) STEPA(q0.y, t + 1) STEPA(q0.z, t + 2) STEPA(q0.w, t + 3)
        q0 = *(const float4*)(eb + t + 16);
        STEPA(q1.x, t + 4) STEPA(q1.y, t + 5) STEPA(q1.z, t + 6) STEPA(q1.w, t + 7)
        q1 = *(const float4*)(eb + t + 20);
        STEPA(q2.x, t + 8) STEPA(q2.y, t + 9) STEPA(q2.z, t + 10) STEPA(q2.w, t + 11)
        q2 = *(const float4*)(eb + t + 24);
        STEPA(q3.x, t + 12) STEPA(q3.y, t + 13) STEPA(q3.z, t + 14) STEPA(q3.w, t + 15)
        q3 = *(const float4*)(eb + t + 28);
        t += 16;
    }
    for (; t <= T_LEN - 1; ++t) { STEPA(eb[t], t) }
    carry[b * 16 + j] = d;
}

// ---------------------------------------------------------------------------
// psi: one thread per (b,t). AT columns via SCALAR path (wave-uniform logAT,
// jj loop not unrolled) -> zero LDS traffic.
__global__ __launch_bounds__(256) void k_psi(const float* __restrict__ dchunk,
                                             const float* __restrict__ logAT,
                                             unsigned char* __restrict__ psi) {
    int tt = blockIdx.x * 256 + threadIdx.x;
    if (tt >= T_LEN - 1) return;
    int b = blockIdx.y;
    const float4* dr = (const float4*)(dchunk + ((size_t)b * T_LEN + tt) * 16);
    float4 v0 = dr[0], v1 = dr[1], v2 = dr[2], v3 = dr[3];
    float dd[16] = {v0.x, v0.y, v0.z, v0.w, v1.x, v1.y, v1.z, v1.w,
                    v2.x, v2.y, v2.z, v2.w, v3.x, v3.y, v3.z, v3.w};
    unsigned long long pk = 0ull;
#pragma clang loop unroll(disable)
    for (int jj = 0; jj < 16; ++jj) {
        const float* col = logAT + (jj << 4);
        float best = __fadd_rn(dd[0], col[0]);
        int arg = 0;
#pragma unroll
        for (int i = 1; i < 16; ++i) {
            float s = __fadd_rn(dd[i], col[i]);
            if (s > best) arg = i;  // first-wins tie rule (i ascending)
            best = fmaxf(best, s);
        }
        pk |= (unsigned long long)arg << (jj * 4);
    }
    unsigned w[4];
#pragma unroll
    for (int q = 0; q < 4; ++q) {
        unsigned h = (unsigned)(pk >> (16 * q)) & 0xFFFFu;
        w[q] = (h & 0xFu) | ((h & 0xF0u) << 4) | ((h & 0xF00u) << 8) | ((h & 0xF000u) << 12);
    }
    int t = 1 + tt;
    *((uint4*)(psi + ((size_t)b * T_LEN + t) * 16)) = make_uint4(w[0], w[1], w[2], w[3]);
}

// ---------------------------------------------------------------------------
// Fused backtrace, one block per batch. All intermediates (chunk maps M,
// boundary states Eb) live in LDS — no threadfence, no global dep-chains.
// Phase A: 16 groups x 4 rounds build 64 chunk maps (psi chunk staged 1KB
// per group). Phase B: tid0 argmax + 64-hop LDS boundary chain. Phase C:
// re-stage chunks, lane 0 walks and writes the path.
__global__ __launch_bounds__(256) void k_back(const unsigned char* __restrict__ psi,
                                              const float* __restrict__ carry,
                                              int* __restrict__ out) {
    __shared__ unsigned char buf[16][1024];
    __shared__ unsigned char Ml[64][16];
    __shared__ unsigned char Ebl[64];
    int b = blockIdx.x, tid = threadIdx.x;
    int grp = tid >> 4, lane = tid & 15;
    const unsigned char* pb = psi + (size_t)b * T_LEN * 16;

    // Phase A: chunk maps
    for (int r = 0; r < 4; ++r) {
        int c = r * 16 + grp;
        int t_lo = c * 64;
        int t_hi = t_lo + 64; if (t_hi > T_LEN - 1) t_hi = T_LEN - 1;
        int n16 = t_hi - t_lo;  // psi rows staged: t in (t_lo, t_hi]
        const uint4* src = (const uint4*)(pb + (size_t)(t_lo + 1) * 16);
        uint4* dst = (uint4*)buf[grp];
        for (int q = lane; q < n16; q += 16) dst[q] = src[q];
        __syncthreads();
        int v = lane;
        for (int t = t_hi; t > t_lo; --t) v = buf[grp][(t - t_lo - 1) * 16 + v];
        Ml[c][lane] = (unsigned char)v;
        __syncthreads();
    }
    // Phase B: argmax(deltaT) (first-wins) + boundary chain in LDS
    if (tid == 0) {
        const float* dT = carry + b * 16;
        float best = dT[0]; int zT = 0;
#pragma unroll
        for (int i = 1; i < 16; ++i) {
            float s = dT[i];
            if (s > best) zT = i;
            best = fmaxf(best, s);
        }
        out[(size_t)b * T_LEN + (T_LEN - 1)] = zT;
        int z = zT;
        for (int c = 63; c >= 0; --c) {
            Ebl[c] = (unsigned char)z;   // state at t_hi(c)
            z = Ml[c][z];                // -> state at t_lo(c) = t_hi(c-1)
        }
    }
    __syncthreads();
    // Phase C: walks
    for (int r = 0; r < 4; ++r) {
        int c = r * 16 + grp;
        int t_lo = c * 64;
        int t_hi = t_lo + 64; if (t_hi > T_LEN - 1) t_hi = T_LEN - 1;
        int n16 = t_hi - t_lo;
        const uint4* src = (const uint4*)(pb + (size_t)(t_lo + 1) * 16);
        uint4* dst = (uint4*)buf[grp];
        for (int q = lane; q < n16; q += 16) dst[q] = src[q];
        __syncthreads();
        if (lane == 0) {
            int cur = Ebl[c];
            int* ob = out + (size_t)b * T_LEN;
            for (int t = t_hi; t > t_lo; --t) {
                cur = buf[grp][(t - t_lo - 1) * 16 + cur];
                ob[t - 1] = cur;
            }
        }
        __syncthreads();
    }
}

// ---------------------------------------------------------------------------
extern "C" void kernel_launch(void* const* d_in, const int* in_sizes, int n_in,
                              void* d_out, int out_size, void* d_ws, size_t ws_size,
                              hipStream_t stream) {
    (void)in_sizes; (void)n_in; (void)out_size; (void)ws_size;
    const float* x   = (const float*)d_in[0];   // [512][4096] fp32
    const float* hmm = (const float*)d_in[1];   // [64][16][16] fp32 (only [0] used)
    int* out = (int*)d_out;                     // [512][4096] int32

    char* w = (char*)d_ws;
    float* logA  = (float*)w;                                  // 1KB
    float* logAT = (float*)(w + 1024);                         // 1KB (4KB slot)
    float* carry = (float*)(w + 4096);                         // 32KB
    unsigned char* psi = (unsigned char*)(w + 4096 + 32768);   // 33.55MB
    float* dchunk = (float*)(psi + (size_t)B_SZ * T_LEN * 16); // 134.2MB
    float* Em = (float*)psi;  // emissions alias psi region (consumed pre-k_psi)

    hipLaunchKernelGGL(k_emit, dim3((B_SZ * T_LEN / 4) / 256), dim3(256), 0, stream,
                       x, Em, hmm, logA, logAT);

    hipLaunchKernelGGL(k_fwd, dim3(B_SZ / 4), dim3(64), 0, stream,
                       Em, logA, dchunk, carry);

    hipLaunchKernelGGL(k_psi, dim3((T_LEN - 1 + 255) / 256, B_SZ), dim3(256), 0, stream,
                       dchunk, logAT, psi);

    hipLaunchKernelGGL(k_back, dim3(B_SZ), dim3(256), 0, stream,
                       psi, carry, out);
}